// Round 2
// baseline (3956.257 us; speedup 1.0000x reference)
//
#include <hip/hip_runtime.h>
#include <stdint.h>

#define A_ 64
#define B_ 256
#define LL_ 2000
#define NF_ 1000000

// fp32 -> bf16 (RNE), returned in low 16 bits
__device__ inline uint32_t f2bf1(float a) {
    uint32_t x = __float_as_uint(a);
    return (x + 0x7fffu + ((x >> 16) & 1u)) >> 16;
}

// ---------------------------------------------------------------------------
// K1 (fused front): conv1 (1->32,K=5,SAME) + conv2 (32->64,K=5,SAME) +
// lin1 (64->128)+relu + lin2 (128->128)+relu, per (b, 128-row l tile).
// Output e[b][l][128] in bf16 (stored as packed uint32 pairs).
// LDS overlay (floats): xs[136]@0 | c1[32*132]@136 | hs[128*65]@4360 (50.7 KB)
// t1[64*129]@0 overlays xs+c1+hs rows<60; MLP half h=1 only reads hs rows>=64,
// which start at float 8520 >= 8256 = t1 end -> safe.
// ---------------------------------------------------------------------------
__global__ __launch_bounds__(256) void k_front(
    const float* __restrict__ x,   const float* __restrict__ w1c,
    const float* __restrict__ b1c, const float* __restrict__ w2c,
    const float* __restrict__ b2c, const float* __restrict__ w1l,
    const float* __restrict__ b1l, const float* __restrict__ w2l,
    const float* __restrict__ b2l, uint32_t* __restrict__ e)
{
    __shared__ float smem[12680];
    float* xs = smem;            // [0,136)
    float* c1 = smem + 136;      // [136,4360)
    float* hs = smem + 4360;     // [4360,12680)
    float* t1 = smem;            // [0,8256) overlay

    const int b  = blockIdx.x >> 4;
    const int l0 = (blockIdx.x & 15) * 128;
    const int t  = threadIdx.x;

    for (int j = t; j < 136; j += 256) {
        int g = l0 - 4 + j;
        xs[j] = (g >= 0 && g < LL_) ? x[b * LL_ + g] : 0.0f;
    }
    __syncthreads();

    // conv1 at positions lp = l0-2+t, t<132. Zero OUTSIDE [0,2000): conv2's
    // SAME padding must see zeros, not conv1(padded-x).
    if (t < 132) {
        int lp = l0 - 2 + t;
        bool valid = (lp >= 0 && lp < LL_);
        float v0 = xs[t], v1 = xs[t+1], v2 = xs[t+2], v3 = xs[t+3], v4 = xs[t+4];
        #pragma unroll
        for (int o = 0; o < 32; ++o) {
            float acc = b1c[o] + v0*w1c[o*5+0] + v1*w1c[o*5+1] + v2*w1c[o*5+2]
                      + v3*w1c[o*5+3] + v4*w1c[o*5+4];
            c1[o*132 + t] = valid ? acc : 0.0f;
        }
    }
    __syncthreads();

    // conv2: thread = (pos ll, out-channel half ob)
    {
        const int ll = t & 127;
        const int ob = __builtin_amdgcn_readfirstlane((t >> 7) * 32);
        float acc[32];
        #pragma unroll
        for (int o = 0; o < 32; ++o) acc[o] = b2c[ob + o];
        for (int i = 0; i < 32; ++i) {
            float v0 = c1[i*132 + ll + 0];
            float v1 = c1[i*132 + ll + 1];
            float v2 = c1[i*132 + ll + 2];
            float v3 = c1[i*132 + ll + 3];
            float v4 = c1[i*132 + ll + 4];
            #pragma unroll
            for (int o = 0; o < 32; ++o) {
                const float* wr = w2c + (ob + o) * 160 + i * 5;  // uniform -> s_load
                acc[o] += v0*wr[0] + v1*wr[1] + v2*wr[2] + v3*wr[3] + v4*wr[4];
            }
        }
        #pragma unroll
        for (int o = 0; o < 32; ++o) hs[ll * 65 + ob + o] = acc[o];
    }
    __syncthreads();

    // MLP on two 64-row halves
    const int l  = t & 63;
    const int jb = __builtin_amdgcn_readfirstlane((t >> 6) * 32);

    for (int h = 0; h < 2; ++h) {
        float xv[64];
        #pragma unroll
        for (int k = 0; k < 64; ++k) xv[k] = hs[(h*64 + l)*65 + k];
        __syncthreads();   // all hs/t1 reads done before t1 writes below

        float acc[32];
        #pragma unroll
        for (int j = 0; j < 32; ++j) {
            const float* wr = w1l + (jb + j) * 64;               // uniform -> s_load
            float a = b1l[jb + j];
            #pragma unroll
            for (int k = 0; k < 64; ++k) a += xv[k] * wr[k];
            acc[j] = fmaxf(a, 0.0f);
        }
        #pragma unroll
        for (int j = 0; j < 32; ++j) t1[l*129 + jb + j] = acc[j];
        __syncthreads();

        float xv2[128];
        #pragma unroll
        for (int k = 0; k < 128; ++k) xv2[k] = t1[l*129 + k];
        float acc2[32];
        #pragma unroll
        for (int j = 0; j < 32; ++j) {
            const float* wr = w2l + (jb + j) * 128;              // uniform -> s_load
            float a = b2l[jb + j];
            #pragma unroll
            for (int k = 0; k < 128; ++k) a += xv2[k] * wr[k];
            acc2[j] = fmaxf(a, 0.0f);
        }
        __syncthreads();   // t1 reads done before rewrite
        #pragma unroll
        for (int j = 0; j < 32; ++j) t1[l*129 + jb + j] = acc2[j];
        __syncthreads();

        // pack-store 64x128 tile as bf16, coalesced uint4 stores
        #pragma unroll
        for (int it = 0; it < 4; ++it) {
            int flat = (t + it * 256) * 8;       // float index into 64x128
            int row = flat >> 7, c = flat & 127;
            int lg = l0 + h*64 + row;
            if (lg < LL_) {
                uint32_t p0 = f2bf1(t1[row*129 + c + 0]) | (f2bf1(t1[row*129 + c + 1]) << 16);
                uint32_t p1 = f2bf1(t1[row*129 + c + 2]) | (f2bf1(t1[row*129 + c + 3]) << 16);
                uint32_t p2 = f2bf1(t1[row*129 + c + 4]) | (f2bf1(t1[row*129 + c + 5]) << 16);
                uint32_t p3 = f2bf1(t1[row*129 + c + 6]) | (f2bf1(t1[row*129 + c + 7]) << 16);
                uint4 v = make_uint4(p0, p1, p2, p3);
                *(uint4*)(e + (size_t)(b * LL_ + lg) * 64 + (c >> 1)) = v;
            }
        }
        // next h: t1 writes happen only after its own post-read barrier -> safe
    }
}

// ---------------------------------------------------------------------------
// K2: lse[b][a] = logsumexp_l( e[b,l,:]·diff[a,:] + base[b,l] ).
// One block per b, 8 waves; lane = a (diff row in VGPRs), l wave-uniform
// (readfirstlane wave id -> e-row loads scalarizable). bf16 unpack via
// shift/and (wave-uniform -> scalar pipe candidates).
// ---------------------------------------------------------------------------
__global__ __launch_bounds__(512) void k_lse(
    const uint32_t* __restrict__ e, const float* __restrict__ diff,
    const float* __restrict__ baseline, const int* __restrict__ regions,
    float* __restrict__ lse)
{
    __shared__ float redm[512];
    __shared__ float reds[512];
    const int b = blockIdx.x;
    const int t = threadIdx.x;
    const int lane = t & 63;                                // = a
    const int w = __builtin_amdgcn_readfirstlane(t >> 6);
    const int rrow = regions[b];

    float dv[128];
    #pragma unroll
    for (int k = 0; k < 128; k += 4) {
        float4 v = *(const float4*)&diff[lane * 128 + k];
        dv[k] = v.x; dv[k+1] = v.y; dv[k+2] = v.z; dv[k+3] = v.w;
    }

    float m = -3.0e38f, s = 0.0f;
    const int lstart = w * 250;                             // 2000 = 8 * 250
    for (int i = 0; i < 250; ++i) {
        const int ll = lstart + i;
        const uint32_t* erow = e + (size_t)(b * LL_ + ll) * 64;  // wave-uniform
        float u0 = 0.f, u1 = 0.f;
        #pragma unroll
        for (int q = 0; q < 64; q += 2) {
            uint32_t pa = erow[q], pb = erow[q + 1];
            u0 += __uint_as_float(pa << 16)          * dv[2*q + 0];
            u1 += __uint_as_float(pa & 0xffff0000u)  * dv[2*q + 1];
            u0 += __uint_as_float(pb << 16)          * dv[2*q + 2];
            u1 += __uint_as_float(pb & 0xffff0000u)  * dv[2*q + 3];
        }
        float u = (u0 + u1) + baseline[rrow * LL_ + ll];
        float mn = fmaxf(m, u);
        s = s * __expf(m - mn) + __expf(u - mn);
        m = mn;
    }
    redm[t] = m;
    reds[t] = s;
    __syncthreads();
    if (t < 64) {
        float M = -3.0e38f;
        #pragma unroll
        for (int ww = 0; ww < 8; ++ww) M = fmaxf(M, redm[ww*64 + t]);
        float S = 0.0f;
        #pragma unroll
        for (int ww = 0; ww < 8; ++ww) S += reds[ww*64 + t] * __expf(redm[ww*64 + t] - M);
        lse[b * 64 + t] = M + __logf(S);
    }
}

// ---------------------------------------------------------------------------
// K3: out[f] = e[b,l,:]·diff[a,:] + base[b,l] - lse[b,a] + ln(256)
// ---------------------------------------------------------------------------
__global__ __launch_bounds__(256) void k_gather(
    const uint32_t* __restrict__ e, const float* __restrict__ diff,
    const float* __restrict__ baseline, const int* __restrict__ regions,
    const int* __restrict__ labels, const int* __restrict__ cellix,
    const int* __restrict__ regionix, const int* __restrict__ binix,
    const float* __restrict__ lse, float* __restrict__ out)
{
    int f = blockIdx.x * 256 + threadIdx.x;
    if (f >= NF_) return;
    int a = labels[cellix[f]];
    int b = regionix[f];
    int l = binix[f];
    const uint32_t* erow = e + (size_t)(b * LL_ + l) * 64;
    const float* dr = diff + a * 128;
    float u0 = 0.f, u1 = 0.f;
    #pragma unroll
    for (int q = 0; q < 64; q += 4) {
        uint4   p  = *(const uint4*)&erow[q];
        float4  d0 = *(const float4*)&dr[2*q + 0];
        float4  d1 = *(const float4*)&dr[2*q + 4];
        u0 += __uint_as_float(p.x << 16)         * d0.x;
        u1 += __uint_as_float(p.x & 0xffff0000u) * d0.y;
        u0 += __uint_as_float(p.y << 16)         * d0.z;
        u1 += __uint_as_float(p.y & 0xffff0000u) * d0.w;
        u0 += __uint_as_float(p.z << 16)         * d1.x;
        u1 += __uint_as_float(p.z & 0xffff0000u) * d1.y;
        u0 += __uint_as_float(p.w << 16)         * d1.z;
        u1 += __uint_as_float(p.w & 0xffff0000u) * d1.w;
    }
    float u = (u0 + u1) + baseline[regions[b] * LL_ + l];
    out[f] = u - lse[b * 64 + a] + 5.545177444479562f;   // + ln(256)
}

extern "C" void kernel_launch(void* const* d_in, const int* in_sizes, int n_in,
                              void* d_out, int out_size, void* d_ws, size_t ws_size,
                              hipStream_t stream)
{
    const float* bincounts = (const float*)d_in[0];
    const float* conv1_w   = (const float*)d_in[1];
    const float* conv1_b   = (const float*)d_in[2];
    const float* conv2_w   = (const float*)d_in[3];
    const float* conv2_b   = (const float*)d_in[4];
    const float* lin1_w    = (const float*)d_in[5];
    const float* lin1_b    = (const float*)d_in[6];
    const float* lin2_w    = (const float*)d_in[7];
    const float* lin2_b    = (const float*)d_in[8];
    const float* baseline  = (const float*)d_in[9];
    const float* diff      = (const float*)d_in[10];
    const int*   regions   = (const int*)d_in[11];
    const int*   labels    = (const int*)d_in[12];
    const int*   cellix    = (const int*)d_in[13];
    const int*   regionix  = (const int*)d_in[14];
    const int*   binix     = (const int*)d_in[15];
    float* out = (float*)d_out;

    // ws layout: e bf16 [B*L*128] = 131,072,000 B | lse f32 [B*64] = 65,536 B
    const size_t e_words = (size_t)B_ * LL_ * 64;    // packed bf16 pairs
    const size_t need = e_words * 4 + (size_t)B_ * 64 * 4;
    if (ws_size < need) return;   // clean failure (poison stays) instead of OOB crash

    uint32_t* e   = (uint32_t*)d_ws;
    float*    lse = (float*)(e + e_words);

    k_front <<<dim3(B_ * 16), dim3(256), 0, stream>>>(bincounts, conv1_w, conv1_b,
                                                      conv2_w, conv2_b, lin1_w, lin1_b,
                                                      lin2_w, lin2_b, e);
    k_lse   <<<dim3(B_), dim3(512), 0, stream>>>(e, diff, baseline, regions, lse);
    k_gather<<<dim3((NF_ + 255) / 256), dim3(256), 0, stream>>>(e, diff, baseline, regions,
                                                                labels, cellix, regionix,
                                                                binix, lse, out);
}

// Round 4
// 644.755 us; speedup vs baseline: 6.1361x; 6.1361x over previous
//
#include <hip/hip_runtime.h>
#include <stdint.h>

typedef unsigned int u32;
typedef short v8s __attribute__((ext_vector_type(8)));
typedef float v4f __attribute__((ext_vector_type(4)));

#define B_ 256
#define NF_ 1000000

__device__ inline u32 f2bf1(float a) {
    u32 x = __float_as_uint(a);
    return (x + 0x7fffu + ((x >> 16) & 1u)) >> 16;
}
__device__ inline float bfval(float a) { return __uint_as_float(f2bf1(a) << 16); }
__device__ inline u32 packbf(float lo, float hi) { return f2bf1(lo) | (f2bf1(hi) << 16); }
__device__ inline v8s as_v8s(uint4 x) { union { uint4 a; v8s b; } u; u.a = x; return u.b; }
__device__ inline v4f mfma16(v8s a, v8s b, v4f c) {
    return __builtin_amdgcn_mfma_f32_16x16x32_bf16(a, b, c, 0, 0, 0);
}

// d_out scratch layout (dword offsets). All regions rewritten every call.
#define OFF_W1T_H 0          // [128][32]  bf16-hi pairs of lin1_w (K=64)
#define OFF_W1T_L 4096       // [128][32]  bf16-lo
#define OFF_W2T_H 8192       // [128][64]  lin2_w (K=128)
#define OFF_W2T_L 16384
#define OFF_DIFF_H 24576     // [64][64]   diff (K=128)
#define OFF_DIFF_L 28672
#define OFF_WCOMP 32768      // [9][64] fp32 composite 9-tap conv weights
#define OFF_BCOMP 33344      // [64]   fp32 composite bias
#define OFF_VC    33408      // [256][4][64] fp32 border corrections (l=0,1,1998,1999)
#define OFF_PART  131072     // [256][16][64][2] lse partials

// ---------------------------------------------------------------------------
// w_prep: pack hi/lo bf16 B-frag images; build composite conv weights/bias and
// exact per-b boundary corrections.
// ---------------------------------------------------------------------------
__global__ __launch_bounds__(256) void w_prep(
    const float* __restrict__ x,   const float* __restrict__ w1c,
    const float* __restrict__ b1c, const float* __restrict__ w2c,
    const float* __restrict__ b2c, const float* __restrict__ w1l,
    const float* __restrict__ w2l, const float* __restrict__ diff,
    u32* __restrict__ scr)
{
    int idx = blockIdx.x * 256 + threadIdx.x;
    float* scf = (float*)scr;
    if (idx < 4096) {                       // w1T: [j=0..127][c=0..31]
        int j = idx >> 5, c = idx & 31;
        float v0 = w1l[j*64 + 2*c], v1 = w1l[j*64 + 2*c + 1];
        scr[OFF_W1T_H + idx] = packbf(v0, v1);
        scr[OFF_W1T_L + idx] = packbf(v0 - bfval(v0), v1 - bfval(v1));
    } else if (idx < 12288) {               // w2T: [j][c=0..63]
        int r = idx - 4096, j = r >> 6, c = r & 63;
        float v0 = w2l[j*128 + 2*c], v1 = w2l[j*128 + 2*c + 1];
        scr[OFF_W2T_H + r] = packbf(v0, v1);
        scr[OFF_W2T_L + r] = packbf(v0 - bfval(v0), v1 - bfval(v1));
    } else if (idx < 16384) {               // diff: [a][c=0..63]
        int r = idx - 12288, a = r >> 6, c = r & 63;
        float v0 = diff[a*128 + 2*c], v1 = diff[a*128 + 2*c + 1];
        scr[OFF_DIFF_H + r] = packbf(v0, v1);
        scr[OFF_DIFF_L + r] = packbf(v0 - bfval(v0), v1 - bfval(v1));
    } else if (idx < 16960) {               // Wcomp[j=0..8][o]
        int r = idx - 16384, j = r >> 6, o = r & 63;
        float s = 0.0f;
        for (int k1 = 0; k1 < 5; ++k1) {
            int k2 = j - k1;
            if (k2 < 0 || k2 > 4) continue;
            for (int i = 0; i < 32; ++i)
                s += w1c[i*5 + k1] * w2c[o*160 + i*5 + k2];
        }
        scf[OFF_WCOMP + r] = s;
    } else if (idx < 17024) {               // Bcomp[o]
        int o = idx - 16960;
        float s = b2c[o];
        for (int i = 0; i < 32; ++i) {
            float b1 = b1c[i];
            for (int k2 = 0; k2 < 5; ++k2) s += w2c[o*160 + i*5 + k2] * b1;
        }
        scf[OFF_BCOMP + o] = s;
    } else if (idx >= 17408 && idx < 82944) {  // Vc[b][q][o]
        int r = idx - 17408;
        int b = r >> 8, q = (r >> 6) & 3, o = r & 63;
        float x0 = x[b*2000], x1 = x[b*2000 + 1];
        float xa = x[b*2000 + 1998], xb = x[b*2000 + 1999];
        float s = 0.0f;
        for (int i = 0; i < 32; ++i) {
            float b1 = b1c[i];
            if (q == 0) {           // l=0: k2=0 -> m=-2, k2=1 -> m=-1
                float hvm2 = b1 + w1c[i*5 + 4]*x0;
                float hvm1 = b1 + w1c[i*5 + 3]*x0 + w1c[i*5 + 4]*x1;
                s += w2c[o*160 + i*5 + 0]*hvm2 + w2c[o*160 + i*5 + 1]*hvm1;
            } else if (q == 1) {    // l=1: k2=0 -> m=-1
                float hvm1 = b1 + w1c[i*5 + 3]*x0 + w1c[i*5 + 4]*x1;
                s += w2c[o*160 + i*5 + 0]*hvm1;
            } else if (q == 2) {    // l=1998: k2=4 -> m=2000
                float hv0 = b1 + w1c[i*5 + 0]*xa + w1c[i*5 + 1]*xb;
                s += w2c[o*160 + i*5 + 4]*hv0;
            } else {                // l=1999: k2=3 -> m=2000, k2=4 -> m=2001
                float hv0 = b1 + w1c[i*5 + 0]*xa + w1c[i*5 + 1]*xb;
                float hv1 = b1 + w1c[i*5 + 0]*xb;
                s += w2c[o*160 + i*5 + 3]*hv0 + w2c[o*160 + i*5 + 4]*hv1;
            }
        }
        scf[OFF_VC + r] = s;
    }
}

// ---------------------------------------------------------------------------
// k_front: exact fp32 composite conv -> lin1+relu (split-bf16 MFMA) ->
// lin2+relu (split-bf16 MFMA) -> e bf16. One block per (b, 128-l tile).
// LDS 67.1 KB (2 blocks/CU). Overlay phases: A1(h/l) -> A2(h/l) -> estage.
// ---------------------------------------------------------------------------
__global__ __launch_bounds__(256, 2) void k_front(
    const float* __restrict__ x,  const float* __restrict__ b1l,
    const float* __restrict__ b2l,
    const float* __restrict__ Wc, const float* __restrict__ Bc,
    const float* __restrict__ Vc,
    const uint4* __restrict__ w1h, const uint4* __restrict__ w1lo,
    const uint4* __restrict__ w2h, const uint4* __restrict__ w2lo,
    u32* __restrict__ e)
{
    __shared__ u32 sm[16776];
    u32* A1h = sm;             // [128][34]  (dead after lin1 A-reads)
    u32* A1l = sm + 4352;      // [128][34]
    u32* A2h = sm;             // [128][65]  (phase 2 overlay)
    u32* A2l = sm + 8320;      // [128][65]
    u32* est = sm;             // [128][65]  (phase 3 overlay)
    float* xsf = (float*)(sm + 16640);   // [136]

    const int b  = blockIdx.x >> 4;
    const int l0 = (blockIdx.x & 15) << 7;
    const int t  = threadIdx.x;
    const int lane = t & 63;
    const int w    = t >> 6;
    const int n16  = lane & 15;
    const int q    = lane >> 4;

    for (int j = t; j < 136; j += 256) {
        int g = l0 - 4 + j;
        xsf[j] = (g >= 0 && g < 2000) ? x[b*2000 + g] : 0.0f;
    }
    __syncthreads();

    // composite conv (exact fp32): thread = (p = t&127, ohalf = t>>7)
    {
        const int p = t & 127;
        const int ohalf = t >> 7;
        const int gl = l0 + p;
        float xr[9];
        #pragma unroll
        for (int j = 0; j < 9; ++j) xr[j] = xsf[p + j];
        float yv[32];
        for (int oi = 0; oi < 32; ++oi) {
            int o = ohalf*32 + oi;                      // wave-uniform
            float y = Bc[o];
            #pragma unroll
            for (int j = 0; j < 9; ++j) y += xr[j] * Wc[j*64 + o];
            if (gl <= 1)                 y -= Vc[(b*4 + gl)*64 + o];
            else if (gl >= 1998 && gl < 2000) y -= Vc[(b*4 + gl - 1996)*64 + o];
            yv[oi] = y;
        }
        #pragma unroll
        for (int ci = 0; ci < 16; ++ci) {
            float v0 = yv[2*ci], v1 = yv[2*ci + 1];
            A1h[p*34 + ohalf*16 + ci] = packbf(v0, v1);
            A1l[p*34 + ohalf*16 + ci] = packbf(v0 - bfval(v0), v1 - bfval(v1));
        }
    }
    __syncthreads();

    // lin1 + relu: M=128 N=128 K=64, split-bf16 (3-term)
    {
        v8s ah[2][2], al[2][2];
        #pragma unroll
        for (int mt = 0; mt < 2; ++mt)
            #pragma unroll
            for (int kc = 0; kc < 2; ++kc) {
                int r = (w*2 + mt)*16 + n16;
                u32 ba = r*34 + kc*16 + q*4;
                ah[mt][kc] = as_v8s(make_uint4(A1h[ba], A1h[ba+1], A1h[ba+2], A1h[ba+3]));
                al[mt][kc] = as_v8s(make_uint4(A1l[ba], A1l[ba+1], A1l[ba+2], A1l[ba+3]));
            }
        v4f acc[2][8];
        #pragma unroll
        for (int nt = 0; nt < 8; ++nt) {
            float bias = b1l[nt*16 + n16];
            acc[0][nt] = (v4f){bias, bias, bias, bias};
            acc[1][nt] = (v4f){bias, bias, bias, bias};
            #pragma unroll
            for (int kc = 0; kc < 2; ++kc) {
                v8s bh = as_v8s(w1h[(nt*16 + n16)*8 + kc*4 + q]);
                v8s bl = as_v8s(w1lo[(nt*16 + n16)*8 + kc*4 + q]);
                #pragma unroll
                for (int mt = 0; mt < 2; ++mt) {
                    acc[mt][nt] = mfma16(ah[mt][kc], bh, acc[mt][nt]);
                    acc[mt][nt] = mfma16(al[mt][kc], bh, acc[mt][nt]);
                    acc[mt][nt] = mfma16(ah[mt][kc], bl, acc[mt][nt]);
                }
            }
        }
        __syncthreads();   // all A1 reads done -> A2 overlay safe
        #pragma unroll
        for (int mt = 0; mt < 2; ++mt)
            #pragma unroll
            for (int nt = 0; nt < 8; ++nt)
                #pragma unroll
                for (int rg = 0; rg < 4; ++rg) {
                    float v = fmaxf(acc[mt][nt][rg], 0.0f);
                    float ov = __shfl_xor(v, 1, 64);
                    if (!(lane & 1)) {
                        int rr = (w*2 + mt)*16 + q*4 + rg;
                        int ci = rr*65 + nt*8 + (n16 >> 1);
                        A2h[ci] = packbf(v, ov);
                        A2l[ci] = packbf(v - bfval(v), ov - bfval(ov));
                    }
                }
    }
    __syncthreads();

    // lin2 + relu: M=128 N=128 K=128, split-bf16 (3-term)
    {
        v8s ah[2][4], al[2][4];
        #pragma unroll
        for (int mt = 0; mt < 2; ++mt)
            #pragma unroll
            for (int kc = 0; kc < 4; ++kc) {
                int r = (w*2 + mt)*16 + n16;
                u32 ba = r*65 + kc*16 + q*4;
                ah[mt][kc] = as_v8s(make_uint4(A2h[ba], A2h[ba+1], A2h[ba+2], A2h[ba+3]));
                al[mt][kc] = as_v8s(make_uint4(A2l[ba], A2l[ba+1], A2l[ba+2], A2l[ba+3]));
            }
        v4f acc[2][8];
        #pragma unroll
        for (int nt = 0; nt < 8; ++nt) {
            float bias = b2l[nt*16 + n16];
            acc[0][nt] = (v4f){bias, bias, bias, bias};
            acc[1][nt] = (v4f){bias, bias, bias, bias};
            #pragma unroll
            for (int kc = 0; kc < 4; ++kc) {
                v8s bh = as_v8s(w2h[(nt*16 + n16)*16 + kc*4 + q]);
                v8s bl = as_v8s(w2lo[(nt*16 + n16)*16 + kc*4 + q]);
                #pragma unroll
                for (int mt = 0; mt < 2; ++mt) {
                    acc[mt][nt] = mfma16(ah[mt][kc], bh, acc[mt][nt]);
                    acc[mt][nt] = mfma16(al[mt][kc], bh, acc[mt][nt]);
                    acc[mt][nt] = mfma16(ah[mt][kc], bl, acc[mt][nt]);
                }
            }
        }
        __syncthreads();   // all A2 reads done -> estage overlay safe
        #pragma unroll
        for (int mt = 0; mt < 2; ++mt)
            #pragma unroll
            for (int nt = 0; nt < 8; ++nt)
                #pragma unroll
                for (int rg = 0; rg < 4; ++rg) {
                    float v = fmaxf(acc[mt][nt][rg], 0.0f);
                    float ov = __shfl_xor(v, 1, 64);
                    if (!(lane & 1)) {
                        int rr = (w*2 + mt)*16 + q*4 + rg;
                        est[rr*65 + nt*8 + (n16 >> 1)] = packbf(v, ov);
                    }
                }
    }
    __syncthreads();

    // coalesced e store
    {
        int r = t >> 1, hh = (t & 1) * 32;
        if (l0 + r < 2000) {
            const u32* src = est + r*65 + hh;
            u32* dst = e + ((size_t)(b*2000 + l0 + r))*64 + hh;
            #pragma unroll
            for (int c = 0; c < 32; c += 4)
                *(uint4*)(dst + c) = make_uint4(src[c], src[c+1], src[c+2], src[c+3]);
        }
    }
}

// ---------------------------------------------------------------------------
// k_lse: per (b, 128-l chunk): U = E @ diffT (diff split hi/lo) + base,
// online (m,s) per column a; partials to d_out scratch.
// ---------------------------------------------------------------------------
__global__ __launch_bounds__(256, 2) void k_lse(
    const u32* __restrict__ e, const uint4* __restrict__ dh,
    const uint4* __restrict__ dl, const float* __restrict__ baseline,
    const int* __restrict__ regions, float* __restrict__ partials)
{
    __shared__ float sred[4][64][2];
    const int b     = blockIdx.x >> 4;
    const int chunk = blockIdx.x & 15;
    const int l0    = chunk << 7;
    const int t     = threadIdx.x;
    const int lane  = t & 63;
    const int w     = t >> 6;
    const int n16   = lane & 15;
    const int q     = lane >> 4;
    const int rrow  = regions[b];
    const int r0    = w * 32;

    v8s af[2][4];
    #pragma unroll
    for (int mt = 0; mt < 2; ++mt) {
        int rl = l0 + r0 + mt*16 + n16;
        int rc = rl < 2000 ? rl : 1999;
        const u32* er = e + ((size_t)(b*2000 + rc))*64;
        #pragma unroll
        for (int kc = 0; kc < 4; ++kc)
            af[mt][kc] = as_v8s(*(const uint4*)(er + kc*16 + q*4));
    }

    float blv[2][4];
    bool  vl[2][4];
    #pragma unroll
    for (int mt = 0; mt < 2; ++mt)
        #pragma unroll
        for (int rg = 0; rg < 4; ++rg) {
            int rl = l0 + r0 + mt*16 + q*4 + rg;
            vl[mt][rg] = rl < 2000;
            blv[mt][rg] = baseline[rrow*2000 + (rl < 2000 ? rl : 1999)];
        }

    #pragma unroll
    for (int nt = 0; nt < 4; ++nt) {
        v4f acc0 = (v4f){0.f,0.f,0.f,0.f}, acc1 = (v4f){0.f,0.f,0.f,0.f};
        #pragma unroll
        for (int kc = 0; kc < 4; ++kc) {
            v8s bh = as_v8s(dh[(nt*16 + n16)*16 + kc*4 + q]);
            v8s bl = as_v8s(dl[(nt*16 + n16)*16 + kc*4 + q]);
            acc0 = mfma16(af[0][kc], bh, acc0);
            acc1 = mfma16(af[1][kc], bh, acc1);
            acc0 = mfma16(af[0][kc], bl, acc0);
            acc1 = mfma16(af[1][kc], bl, acc1);
        }
        float m = -3.0e38f, s = 0.0f;
        #pragma unroll
        for (int rg = 0; rg < 4; ++rg) {
            float u = acc0[rg] + blv[0][rg];
            if (vl[0][rg]) {
                float mn = fmaxf(m, u);
                s = s * __expf(m - mn) + __expf(u - mn);
                m = mn;
            }
        }
        #pragma unroll
        for (int rg = 0; rg < 4; ++rg) {
            float u = acc1[rg] + blv[1][rg];
            if (vl[1][rg]) {
                float mn = fmaxf(m, u);
                s = s * __expf(m - mn) + __expf(u - mn);
                m = mn;
            }
        }
        #pragma unroll
        for (int off = 16; off < 64; off <<= 1) {
            float m2 = __shfl_xor(m, off, 64);
            float s2 = __shfl_xor(s, off, 64);
            float mn = fmaxf(m, m2);
            s = s * __expf(m - mn) + s2 * __expf(m2 - mn);
            m = mn;
        }
        if (q == 0) {
            sred[w][nt*16 + n16][0] = m;
            sred[w][nt*16 + n16][1] = s;
        }
    }
    __syncthreads();
    if (t < 64) {
        float m = sred[0][t][0], s = sred[0][t][1];
        #pragma unroll
        for (int ww = 1; ww < 4; ++ww) {
            float m2 = sred[ww][t][0], s2 = sred[ww][t][1];
            float mn = fmaxf(m, m2);
            s = s * __expf(m - mn) + s2 * __expf(m2 - mn);
            m = mn;
        }
        partials[((b*16 + chunk)*64 + t)*2 + 0] = m;
        partials[((b*16 + chunk)*64 + t)*2 + 1] = s;
    }
}

__global__ __launch_bounds__(64) void k_red(
    const float* __restrict__ partials, float* __restrict__ lse)
{
    int b = blockIdx.x, a = threadIdx.x;
    float m = -3.0e38f, s = 0.0f;
    for (int c = 0; c < 16; ++c) {
        float pm = partials[((b*16 + c)*64 + a)*2 + 0];
        float ps = partials[((b*16 + c)*64 + a)*2 + 1];
        float mn = fmaxf(m, pm);
        s = s * __expf(m - mn) + ps * __expf(pm - mn);
        m = mn;
    }
    lse[b*64 + a] = m + __logf(s);
}

__global__ __launch_bounds__(256) void k_gather(
    const u32* __restrict__ e, const float* __restrict__ diff,
    const float* __restrict__ baseline, const int* __restrict__ regions,
    const int* __restrict__ labels, const int* __restrict__ cellix,
    const int* __restrict__ regionix, const int* __restrict__ binix,
    const float* __restrict__ lse, float* __restrict__ out)
{
    int f = blockIdx.x * 256 + threadIdx.x;
    if (f >= NF_) return;
    int a = labels[cellix[f]];
    int b = regionix[f];
    int l = binix[f];
    const u32* erow = e + (size_t)(b*2000 + l)*64;
    const float* dr = diff + a*128;
    float u0 = 0.f, u1 = 0.f;
    #pragma unroll
    for (int qq = 0; qq < 64; qq += 4) {
        uint4  p  = *(const uint4*)&erow[qq];
        float4 d0 = *(const float4*)&dr[2*qq + 0];
        float4 d1 = *(const float4*)&dr[2*qq + 4];
        u0 += __uint_as_float(p.x << 16)         * d0.x;
        u1 += __uint_as_float(p.x & 0xffff0000u) * d0.y;
        u0 += __uint_as_float(p.y << 16)         * d0.z;
        u1 += __uint_as_float(p.y & 0xffff0000u) * d0.w;
        u0 += __uint_as_float(p.z << 16)         * d1.x;
        u1 += __uint_as_float(p.z & 0xffff0000u) * d1.y;
        u0 += __uint_as_float(p.w << 16)         * d1.z;
        u1 += __uint_as_float(p.w & 0xffff0000u) * d1.w;
    }
    float u = (u0 + u1) + baseline[regions[b]*2000 + l];
    out[f] = u - lse[b*64 + a] + 5.545177444479562f;   // + ln(256)
}

extern "C" void kernel_launch(void* const* d_in, const int* in_sizes, int n_in,
                              void* d_out, int out_size, void* d_ws, size_t ws_size,
                              hipStream_t stream)
{
    const float* bincounts = (const float*)d_in[0];
    const float* conv1_w   = (const float*)d_in[1];
    const float* conv1_b   = (const float*)d_in[2];
    const float* conv2_w   = (const float*)d_in[3];
    const float* conv2_b   = (const float*)d_in[4];
    const float* lin1_w    = (const float*)d_in[5];
    const float* lin1_b    = (const float*)d_in[6];
    const float* lin2_w    = (const float*)d_in[7];
    const float* lin2_b    = (const float*)d_in[8];
    const float* baseline  = (const float*)d_in[9];
    const float* diff      = (const float*)d_in[10];
    const int*   regions   = (const int*)d_in[11];
    const int*   labels    = (const int*)d_in[12];
    const int*   cellix    = (const int*)d_in[13];
    const int*   regionix  = (const int*)d_in[14];
    const int*   binix     = (const int*)d_in[15];
    float* out = (float*)d_out;
    u32*   scr = (u32*)d_out;    // d_out doubles as scratch until k_gather

    const size_t e_words = (size_t)B_ * 2000 * 64;      // packed bf16 pairs
    const size_t need = e_words*4 + (size_t)B_*64*4;
    if (ws_size < need) return;
    u32*   e   = (u32*)d_ws;
    float* lse = (float*)(e + e_words);

    const float* scf = (const float*)scr;
    float* partials = (float*)(scr + OFF_PART);

    w_prep <<<dim3(324), dim3(256), 0, stream>>>(bincounts, conv1_w, conv1_b, conv2_w,
                                                 conv2_b, lin1_w, lin2_w, diff, scr);
    k_front<<<dim3(B_*16), dim3(256), 0, stream>>>(bincounts, lin1_b, lin2_b,
                                                   scf + OFF_WCOMP, scf + OFF_BCOMP,
                                                   scf + OFF_VC,
                                                   (const uint4*)(scr + OFF_W1T_H),
                                                   (const uint4*)(scr + OFF_W1T_L),
                                                   (const uint4*)(scr + OFF_W2T_H),
                                                   (const uint4*)(scr + OFF_W2T_L), e);
    k_lse  <<<dim3(B_*16), dim3(256), 0, stream>>>(e, (const uint4*)(scr + OFF_DIFF_H),
                                                   (const uint4*)(scr + OFF_DIFF_L),
                                                   baseline, regions, partials);
    k_red  <<<dim3(B_), dim3(64), 0, stream>>>(partials, lse);
    k_gather<<<dim3((NF_+255)/256), dim3(256), 0, stream>>>(e, diff, baseline, regions,
                                                            labels, cellix, regionix,
                                                            binix, lse, out);
}